// Round 1
// baseline (476.654 us; speedup 1.0000x reference)
//
#include <hip/hip_runtime.h>
#include <math.h>

// Problem constants (fixed by the reference)
#define NPTS 500000
#define SCALE 0.35355339059327373f   // 1/sqrt(8)
#define NTILES 7813                  // ceil(500000/64)
#define TPB 8                        // tiles per block
#define GRID ((NTILES + TPB - 1) / TPB)

// ws layout (float offsets):
// [0,4096)      WqT[k][c] = Wq[c][k]
// [4096,8192)   WoT[c][c'] = Wo[c'][c]
// [8192,8704)   khs[b][c] = (k@Wk.T + bk)*scale
// [8704,9216)   vh[b][c]  = v@Wv.T + bv
// [9216,10240)  z as double[512]  (byte offset 36864, 8-aligned)

__global__ void prep_kernel(const float* __restrict__ kin, const float* __restrict__ vin,
                            const float* __restrict__ Wq, const float* __restrict__ Wk,
                            const float* __restrict__ bk, const float* __restrict__ Wv,
                            const float* __restrict__ bv, const float* __restrict__ Wo,
                            float* __restrict__ ws) {
    const int tid = threadIdx.x;
    float* WqT = ws;
    float* WoT = ws + 4096;
    float* khs = ws + 8192;
    float* vh  = ws + 8704;
    double* zg = (double*)(ws + 9216);
    for (int idx = tid; idx < 4096; idx += 256) {
        int a = idx >> 6, b = idx & 63;
        WqT[idx] = Wq[b * 64 + a];
        WoT[idx] = Wo[b * 64 + a];
    }
    for (int idx = tid; idx < 512; idx += 256) {
        int b = idx >> 6, c = idx & 63;
        float dk = 0.f, dv = 0.f;
        for (int j = 0; j < 64; ++j) {
            dk = fmaf(kin[b * 64 + j], Wk[c * 64 + j], dk);
            dv = fmaf(vin[b * 64 + j], Wv[c * 64 + j], dv);
        }
        khs[idx] = (dk + bk[c]) * SCALE;
        vh[idx]  = dv + bv[c];
        zg[idx]  = 0.0;
    }
}

__global__ __launch_bounds__(256) void passA_kernel(const float* __restrict__ q,
                                                    const int* __restrict__ batch,
                                                    const float* __restrict__ bq,
                                                    float* __restrict__ ws) {
    __shared__ __align__(16) float qT[64 * 68];   // qT[k][p], stride 68
    __shared__ __align__(16) float wq[4096];      // WqT[k][c]
    __shared__ __align__(16) float khs_l[512];
    __shared__ __align__(16) float bq_l[64];
    __shared__ int bs[64];
    __shared__ double zred[16 * 64];

    const float* WqT   = ws;
    const float* khs_g = ws + 8192;
    double* zg = (double*)(ws + 9216);

    const int tid = threadIdx.x;
    const int tx = tid & 15, ty = tid >> 4;   // c0 = 4*tx, p0 = 4*ty

    for (int idx = tid; idx < 4096; idx += 256) wq[idx] = WqT[idx];
    for (int idx = tid; idx < 512; idx += 256) khs_l[idx] = khs_g[idx];
    if (tid < 64) bq_l[tid] = bq[tid];

    float zacc[4] = {0.f, 0.f, 0.f, 0.f};
    int cur_b = -1;

    // flush: per-thread partials -> double LDS tree -> one f64 atomic per channel.
    // Only called under block-uniform conditions (cur_b / tile b are uniform).
    auto flushz = [&](int b) {
        if (b >= 0) {
            __syncthreads();
            #pragma unroll
            for (int j = 0; j < 4; ++j) zred[ty * 64 + 4 * tx + j] = (double)zacc[j];
            __syncthreads();
            if (tid < 64) {
                double s = 0.0;
                #pragma unroll
                for (int r = 0; r < 16; ++r) s += zred[r * 64 + tid];
                unsafeAtomicAdd(&zg[b * 64 + tid], s);
            }
            zacc[0] = zacc[1] = zacc[2] = zacc[3] = 0.f;
        }
    };

    const int t0 = blockIdx.x * TPB;
    const int t1 = (t0 + TPB < NTILES) ? (t0 + TPB) : NTILES;
    __syncthreads();

    float bqa[4];
    { float4 b4 = *(const float4*)&bq_l[4 * tx];
      bqa[0] = b4.x; bqa[1] = b4.y; bqa[2] = b4.z; bqa[3] = b4.w; }

    for (int t = t0; t < t1; ++t) {
        const int p0g = t * 64;
        // stage q tile transposed + batch
        #pragma unroll
        for (int r = 0; r < 4; ++r) {
            int p = ty + r * 16;
            int gp = p0g + p;
            float4 val = make_float4(0.f, 0.f, 0.f, 0.f);
            if (gp < NPTS) val = ((const float4*)q)[gp * 16 + tx];
            qT[(tx * 4 + 0) * 68 + p] = val.x;
            qT[(tx * 4 + 1) * 68 + p] = val.y;
            qT[(tx * 4 + 2) * 68 + p] = val.z;
            qT[(tx * 4 + 3) * 68 + p] = val.w;
        }
        if (tid < 64) {
            int gp = p0g + tid;
            bs[tid] = batch[gp < NPTS ? gp : (NPTS - 1)];
        }
        __syncthreads();
        const int b_lo = bs[0], b_hi = bs[63];  // batch sorted -> uniform iff equal
        const bool uni = (b_lo == b_hi);
        if (uni) {
            if (cur_b != b_lo) { flushz(cur_b); cur_b = b_lo; }
        } else {
            flushz(cur_b); cur_b = -1;
        }

        // GEMM1: qp[p][c] = sum_k q[p][k] * Wq[c][k]
        float acc[4][4] = {};
        #pragma unroll 16
        for (int kk = 0; kk < 64; ++kk) {
            float4 a4 = *(const float4*)&qT[kk * 68 + 4 * ty];
            float4 w4 = *(const float4*)&wq[kk * 64 + 4 * tx];
            float av[4] = {a4.x, a4.y, a4.z, a4.w};
            float wv[4] = {w4.x, w4.y, w4.z, w4.w};
            #pragma unroll
            for (int i = 0; i < 4; ++i)
                #pragma unroll
                for (int j = 0; j < 4; ++j)
                    acc[i][j] = fmaf(av[i], wv[j], acc[i][j]);
        }

        if (uni) {
            float kh[4];
            { float4 k4 = *(const float4*)&khs_l[b_lo * 64 + 4 * tx];
              kh[0] = k4.x; kh[1] = k4.y; kh[2] = k4.z; kh[3] = k4.w; }
            #pragma unroll
            for (int j = 0; j < 4; ++j) {
                float ps = 0.f;
                #pragma unroll
                for (int i = 0; i < 4; ++i) {
                    int gp = p0g + 4 * ty + i;
                    float e = (gp < NPTS) ? expf((acc[i][j] + bqa[j]) * kh[j]) : 0.f;
                    ps += e;
                }
                zacc[j] += ps;
            }
        } else {
            // rare boundary tile (<=7 in the whole grid): per-point global f64 atomics
            #pragma unroll
            for (int i = 0; i < 4; ++i) {
                int pl = 4 * ty + i, gp = p0g + pl;
                int bi = bs[pl];
                if (gp < NPTS) {
                    #pragma unroll
                    for (int j = 0; j < 4; ++j) {
                        float e = expf((acc[i][j] + bqa[j]) * khs_l[bi * 64 + 4 * tx + j]);
                        unsafeAtomicAdd(&zg[bi * 64 + 4 * tx + j], (double)e);
                    }
                }
            }
        }
        __syncthreads();   // qT about to be restaged
    }
    flushz(cur_b);
}

__global__ __launch_bounds__(256) void passB_kernel(const float* __restrict__ q,
                                                    const int* __restrict__ batch,
                                                    const float* __restrict__ bq,
                                                    const float* __restrict__ bo,
                                                    const float* __restrict__ ws,
                                                    float* __restrict__ out) {
    __shared__ __align__(16) float qT[64 * 68];   // reused for t^T after GEMM1
    __shared__ __align__(16) float wq[4096];
    __shared__ __align__(16) float wo[4096];
    __shared__ __align__(16) float khs_l[512];
    __shared__ __align__(16) float w_l[512];      // vh/z
    __shared__ __align__(16) float bq_l[64];
    __shared__ __align__(16) float bo_l[64];
    __shared__ int bs[64];

    const float* WqT   = ws;
    const float* WoT   = ws + 4096;
    const float* khs_g = ws + 8192;
    const float* vh_g  = ws + 8704;
    const double* zg   = (const double*)(ws + 9216);

    const int tid = threadIdx.x;
    const int tx = tid & 15, ty = tid >> 4;

    for (int idx = tid; idx < 4096; idx += 256) { wq[idx] = WqT[idx]; wo[idx] = WoT[idx]; }
    for (int idx = tid; idx < 512; idx += 256) {
        khs_l[idx] = khs_g[idx];
        w_l[idx] = (float)((double)vh_g[idx] / zg[idx]);
    }
    if (tid < 64) { bq_l[tid] = bq[tid]; bo_l[tid] = bo[tid]; }

    const int t0 = blockIdx.x * TPB;
    const int t1 = (t0 + TPB < NTILES) ? (t0 + TPB) : NTILES;
    __syncthreads();

    float bqa[4], boa[4];
    { float4 b4 = *(const float4*)&bq_l[4 * tx];
      bqa[0] = b4.x; bqa[1] = b4.y; bqa[2] = b4.z; bqa[3] = b4.w; }
    { float4 b4 = *(const float4*)&bo_l[4 * tx];
      boa[0] = b4.x; boa[1] = b4.y; boa[2] = b4.z; boa[3] = b4.w; }

    for (int t = t0; t < t1; ++t) {
        const int p0g = t * 64;
        #pragma unroll
        for (int r = 0; r < 4; ++r) {
            int p = ty + r * 16;
            int gp = p0g + p;
            float4 val = make_float4(0.f, 0.f, 0.f, 0.f);
            if (gp < NPTS) val = ((const float4*)q)[gp * 16 + tx];
            qT[(tx * 4 + 0) * 68 + p] = val.x;
            qT[(tx * 4 + 1) * 68 + p] = val.y;
            qT[(tx * 4 + 2) * 68 + p] = val.z;
            qT[(tx * 4 + 3) * 68 + p] = val.w;
        }
        if (tid < 64) {
            int gp = p0g + tid;
            bs[tid] = batch[gp < NPTS ? gp : (NPTS - 1)];
        }
        __syncthreads();

        // GEMM1: qp
        float acc[4][4] = {};
        #pragma unroll 16
        for (int kk = 0; kk < 64; ++kk) {
            float4 a4 = *(const float4*)&qT[kk * 68 + 4 * ty];
            float4 w4 = *(const float4*)&wq[kk * 64 + 4 * tx];
            float av[4] = {a4.x, a4.y, a4.z, a4.w};
            float wv[4] = {w4.x, w4.y, w4.z, w4.w};
            #pragma unroll
            for (int i = 0; i < 4; ++i)
                #pragma unroll
                for (int j = 0; j < 4; ++j)
                    acc[i][j] = fmaf(av[i], wv[j], acc[i][j]);
        }

        // t = exp(attn) * vh/z   (per-point segment lookup; handles boundary tiles too)
        float tv[4][4];
        #pragma unroll
        for (int i = 0; i < 4; ++i) {
            int pl = 4 * ty + i, gp = p0g + pl;
            int bi = bs[pl];
            float kh[4], wv[4];
            { float4 k4 = *(const float4*)&khs_l[bi * 64 + 4 * tx];
              kh[0] = k4.x; kh[1] = k4.y; kh[2] = k4.z; kh[3] = k4.w; }
            { float4 w4 = *(const float4*)&w_l[bi * 64 + 4 * tx];
              wv[0] = w4.x; wv[1] = w4.y; wv[2] = w4.z; wv[3] = w4.w; }
            bool valid = (gp < NPTS);
            #pragma unroll
            for (int j = 0; j < 4; ++j)
                tv[i][j] = valid ? expf((acc[i][j] + bqa[j]) * kh[j]) * wv[j] : 0.f;
        }
        __syncthreads();    // everyone done reading qT
        #pragma unroll
        for (int j = 0; j < 4; ++j) {
            float4 t4 = make_float4(tv[0][j], tv[1][j], tv[2][j], tv[3][j]);
            *(float4*)&qT[(4 * tx + j) * 68 + 4 * ty] = t4;   // tT[c][p]
        }
        __syncthreads();

        // GEMM2: out[p][c'] = sum_c t[p][c] * Wo[c'][c] + bo
        float acc2[4][4] = {};
        #pragma unroll 16
        for (int cc = 0; cc < 64; ++cc) {
            float4 a4 = *(const float4*)&qT[cc * 68 + 4 * ty];
            float4 w4 = *(const float4*)&wo[cc * 64 + 4 * tx];
            float av[4] = {a4.x, a4.y, a4.z, a4.w};
            float wv[4] = {w4.x, w4.y, w4.z, w4.w};
            #pragma unroll
            for (int i = 0; i < 4; ++i)
                #pragma unroll
                for (int j = 0; j < 4; ++j)
                    acc2[i][j] = fmaf(av[i], wv[j], acc2[i][j]);
        }
        #pragma unroll
        for (int i = 0; i < 4; ++i) {
            int gp = p0g + 4 * ty + i;
            if (gp < NPTS) {
                float4 o = make_float4(acc2[i][0] + boa[0], acc2[i][1] + boa[1],
                                       acc2[i][2] + boa[2], acc2[i][3] + boa[3]);
                ((float4*)out)[gp * 16 + tx] = o;
            }
        }
        __syncthreads();
    }
}

extern "C" void kernel_launch(void* const* d_in, const int* in_sizes, int n_in,
                              void* d_out, int out_size, void* d_ws, size_t ws_size,
                              hipStream_t stream) {
    const float* q   = (const float*)d_in[0];
    const float* k   = (const float*)d_in[1];
    const float* v   = (const float*)d_in[2];
    const float* Wq  = (const float*)d_in[3];
    const float* bq  = (const float*)d_in[4];
    const float* Wk  = (const float*)d_in[5];
    const float* bk  = (const float*)d_in[6];
    const float* Wv  = (const float*)d_in[7];
    const float* bv  = (const float*)d_in[8];
    const float* Wo  = (const float*)d_in[9];
    const float* bo  = (const float*)d_in[10];
    const int*  batch = (const int*)d_in[11];
    float* out = (float*)d_out;
    float* ws  = (float*)d_ws;

    prep_kernel<<<1, 256, 0, stream>>>(k, v, Wq, Wk, bk, Wv, bv, Wo, ws);
    passA_kernel<<<GRID, 256, 0, stream>>>(q, batch, bq, ws);
    passB_kernel<<<GRID, 256, 0, stream>>>(q, batch, bq, bo, ws, out);
}

// Round 2
// 345.173 us; speedup vs baseline: 1.3809x; 1.3809x over previous
//
#include <hip/hip_runtime.h>
#include <math.h>

// Problem constants (fixed by the reference)
#define NPTS 500000
#define SCALE 0.35355339059327373f   // 1/sqrt(8)
#define NTILES 7813                  // ceil(500000/64)
#define TPB 4                        // tiles per block
#define GRID ((NTILES + TPB - 1) / TPB)

// Padded transposed-tile layout: element (k,p) of a 64x64 tile lives at
//   (k>>2)*276 + (k&3)*68 + p
// Group stride 276 floats == 20 (mod 32) -> staging writes from 16 lanes hit
// all 32 banks 2-way (free, m136); reads stay 16B-aligned for ds_read_b128.
#define QT_IDX(k, p) ((((k) >> 2) * 276) + (((k) & 3) * 68) + (p))
#define QT_SIZE 4416

// ws layout (float offsets):
// [0,4096)      WqT[k][c] = Wq[c][k]
// [4096,8192)   WoT[c][c'] = Wo[c'][c]
// [8192,8704)   khs[b][c] = (k@Wk.T + bk)*scale
// [8704,9216)   vh[b][c]  = v@Wv.T + bv
// [9216,10240)  z as double[512]  (byte offset 36864, 8-aligned)

__global__ void prep_kernel(const float* __restrict__ kin, const float* __restrict__ vin,
                            const float* __restrict__ Wq, const float* __restrict__ Wk,
                            const float* __restrict__ bk, const float* __restrict__ Wv,
                            const float* __restrict__ bv, const float* __restrict__ Wo,
                            float* __restrict__ ws) {
    const int gid = blockIdx.x * 256 + threadIdx.x;
    float* WqT = ws;
    float* WoT = ws + 4096;
    float* khs = ws + 8192;
    float* vh  = ws + 8704;
    double* zg = (double*)(ws + 9216);
    for (int idx = gid; idx < 4096; idx += 8 * 256) {
        int a = idx >> 6, b = idx & 63;
        WqT[idx] = Wq[b * 64 + a];
        WoT[idx] = Wo[b * 64 + a];
    }
    for (int idx = gid; idx < 512; idx += 8 * 256) {
        int b = idx >> 6, c = idx & 63;
        float dk = 0.f, dv = 0.f;
        #pragma unroll 8
        for (int j = 0; j < 64; ++j) {
            dk = fmaf(kin[b * 64 + j], Wk[c * 64 + j], dk);
            dv = fmaf(vin[b * 64 + j], Wv[c * 64 + j], dv);
        }
        khs[idx] = (dk + bk[c]) * SCALE;
        vh[idx]  = dv + bv[c];
        zg[idx]  = 0.0;
    }
}

// passA: e = exp((q@Wq.T + bq) * khs[batch]) -> e_out (aliases d_out), z-accum (f64 global)
__global__ __launch_bounds__(256, 4) void passA_kernel(const float* __restrict__ q,
                                                       const int* __restrict__ batch,
                                                       const float* __restrict__ bq,
                                                       float* __restrict__ ws,
                                                       float* __restrict__ e_out) {
    __shared__ __align__(16) float qT[QT_SIZE];
    __shared__ __align__(16) float wq[4096];
    __shared__ __align__(16) float khs_l[512];
    __shared__ __align__(16) float bq_l[64];
    __shared__ int bs[64];
    __shared__ __align__(16) float zred[4 * 64];

    const float* WqT   = ws;
    const float* khs_g = ws + 8192;
    double* zg = (double*)(ws + 9216);

    const int tid = threadIdx.x;
    const int tx = tid & 15, ty = tid >> 4;   // thread owns ch 4tx..4tx+3, pts 4ty..4ty+3

    for (int idx = tid; idx < 1024; idx += 256) ((float4*)wq)[idx] = ((const float4*)WqT)[idx];
    for (int idx = tid; idx < 128; idx += 256) ((float4*)khs_l)[idx] = ((const float4*)khs_g)[idx];
    if (tid < 64) bq_l[tid] = bq[tid];

    float zacc[4] = {0.f, 0.f, 0.f, 0.f};
    int cur_b = -1;

    // per-thread fp32 partials -> wave shuffle over ty -> LDS -> one f64 atomic/channel.
    // Called only under block-uniform conditions.
    auto flushz = [&](int b) {
        if (b < 0) return;
        float v0 = zacc[0], v1 = zacc[1], v2 = zacc[2], v3 = zacc[3];
        v0 += __shfl_xor(v0, 16); v0 += __shfl_xor(v0, 32);
        v1 += __shfl_xor(v1, 16); v1 += __shfl_xor(v1, 32);
        v2 += __shfl_xor(v2, 16); v2 += __shfl_xor(v2, 32);
        v3 += __shfl_xor(v3, 16); v3 += __shfl_xor(v3, 32);
        __syncthreads();                 // zred reuse guard
        if ((tid & 48) == 0) {
            int wv = tid >> 6;
            *(float4*)&zred[wv * 64 + 4 * tx] = make_float4(v0, v1, v2, v3);
        }
        __syncthreads();
        if (tid < 64) {
            float s = zred[tid] + zred[64 + tid] + zred[128 + tid] + zred[192 + tid];
            unsafeAtomicAdd(&zg[b * 64 + tid], (double)s);
        }
        zacc[0] = zacc[1] = zacc[2] = zacc[3] = 0.f;
    };

    const int t0 = blockIdx.x * TPB;
    const int t1 = (t0 + TPB < NTILES) ? (t0 + TPB) : NTILES;
    __syncthreads();

    float bqa[4];
    { float4 b4 = *(const float4*)&bq_l[4 * tx];
      bqa[0] = b4.x; bqa[1] = b4.y; bqa[2] = b4.z; bqa[3] = b4.w; }

    for (int t = t0; t < t1; ++t) {
        const int p0g = t * 64;
        #pragma unroll
        for (int r = 0; r < 4; ++r) {
            int p = ty + r * 16;
            int gp = p0g + p;
            float4 val = make_float4(0.f, 0.f, 0.f, 0.f);
            if (gp < NPTS) val = ((const float4*)q)[gp * 16 + tx];
            qT[QT_IDX(4 * tx + 0, p)] = val.x;
            qT[QT_IDX(4 * tx + 1, p)] = val.y;
            qT[QT_IDX(4 * tx + 2, p)] = val.z;
            qT[QT_IDX(4 * tx + 3, p)] = val.w;
        }
        if (tid < 64) {
            int gp = p0g + tid;
            bs[tid] = batch[gp < NPTS ? gp : (NPTS - 1)];
        }
        __syncthreads();
        const int b_lo = bs[0], b_hi = bs[63];
        const bool uni = (b_lo == b_hi);
        if (uni) {
            if (cur_b != b_lo) { flushz(cur_b); cur_b = b_lo; }
        } else {
            flushz(cur_b); cur_b = -1;
        }

        // GEMM1: qp[p][c] = sum_k q[p][k] * Wq[c][k]
        float acc[4][4] = {};
        #pragma unroll 4
        for (int kg = 0; kg < 16; ++kg) {
            #pragma unroll
            for (int kj = 0; kj < 4; ++kj) {
                float4 a4 = *(const float4*)&qT[kg * 276 + kj * 68 + 4 * ty];
                float4 w4 = *(const float4*)&wq[(kg * 4 + kj) * 64 + 4 * tx];
                float av[4] = {a4.x, a4.y, a4.z, a4.w};
                float wv[4] = {w4.x, w4.y, w4.z, w4.w};
                #pragma unroll
                for (int i = 0; i < 4; ++i)
                    #pragma unroll
                    for (int j = 0; j < 4; ++j)
                        acc[i][j] = fmaf(av[i], wv[j], acc[i][j]);
            }
        }

        // e = exp(attn); store to e_out; accumulate z
        float ev[4][4];
        #pragma unroll
        for (int i = 0; i < 4; ++i) {
            int pl = 4 * ty + i, gp = p0g + pl;
            int bi = bs[pl];
            float4 k4 = *(const float4*)&khs_l[bi * 64 + 4 * tx];
            float kh[4] = {k4.x, k4.y, k4.z, k4.w};
            bool valid = (gp < NPTS);
            #pragma unroll
            for (int j = 0; j < 4; ++j)
                ev[i][j] = valid ? __expf((acc[i][j] + bqa[j]) * kh[j]) : 0.f;
            if (valid)
                ((float4*)e_out)[gp * 16 + tx] = make_float4(ev[i][0], ev[i][1], ev[i][2], ev[i][3]);
        }

        if (uni) {
            #pragma unroll
            for (int j = 0; j < 4; ++j)
                zacc[j] += (ev[0][j] + ev[1][j]) + (ev[2][j] + ev[3][j]);
        } else {
            // rare boundary tile (<=7 in the whole grid)
            #pragma unroll
            for (int i = 0; i < 4; ++i) {
                int pl = 4 * ty + i, gp = p0g + pl;
                int bi = bs[pl];
                if (gp < NPTS) {
                    #pragma unroll
                    for (int j = 0; j < 4; ++j)
                        unsafeAtomicAdd(&zg[bi * 64 + 4 * tx + j], (double)ev[i][j]);
                }
            }
        }
        __syncthreads();   // qT about to be restaged
    }
    flushz(cur_b);
}

// passB: out = (e * (vh/z)[batch]) @ Wo.T + bo ; e read from d_out, out written in place
__global__ __launch_bounds__(256, 4) void passB_kernel(const int* __restrict__ batch,
                                                       const float* __restrict__ bo,
                                                       const float* __restrict__ ws,
                                                       float* __restrict__ out) {
    __shared__ __align__(16) float tT[QT_SIZE];
    __shared__ __align__(16) float wo[4096];
    __shared__ __align__(16) float w_l[512];
    __shared__ __align__(16) float bo_l[64];

    const float* WoT  = ws + 4096;
    const float* vh_g = ws + 8704;
    const double* zg  = (const double*)(ws + 9216);

    const int tid = threadIdx.x;
    const int tx = tid & 15, ty = tid >> 4;

    for (int idx = tid; idx < 1024; idx += 256) ((float4*)wo)[idx] = ((const float4*)WoT)[idx];
    for (int idx = tid; idx < 512; idx += 256)
        w_l[idx] = (float)((double)vh_g[idx] / zg[idx]);
    if (tid < 64) bo_l[tid] = bo[tid];

    const int t0 = blockIdx.x * TPB;
    const int t1 = (t0 + TPB < NTILES) ? (t0 + TPB) : NTILES;
    __syncthreads();

    float boa[4];
    { float4 b4 = *(const float4*)&bo_l[4 * tx];
      boa[0] = b4.x; boa[1] = b4.y; boa[2] = b4.z; boa[3] = b4.w; }

    for (int t = t0; t < t1; ++t) {
        const int p0g = t * 64;
        // stage t = e * w[batch], transposed
        #pragma unroll
        for (int r = 0; r < 4; ++r) {
            int p = ty + r * 16;
            int gp = p0g + p;
            float4 ev = make_float4(0.f, 0.f, 0.f, 0.f);
            int bi = 0;
            if (gp < NPTS) { ev = ((const float4*)out)[gp * 16 + tx]; bi = batch[gp]; }
            float4 wv = *(const float4*)&w_l[bi * 64 + 4 * tx];
            tT[QT_IDX(4 * tx + 0, p)] = ev.x * wv.x;
            tT[QT_IDX(4 * tx + 1, p)] = ev.y * wv.y;
            tT[QT_IDX(4 * tx + 2, p)] = ev.z * wv.z;
            tT[QT_IDX(4 * tx + 3, p)] = ev.w * wv.w;
        }
        __syncthreads();

        // GEMM2: out[p][c'] = sum_c t[p][c] * Wo[c'][c] + bo
        float acc[4][4] = {};
        #pragma unroll 4
        for (int cg = 0; cg < 16; ++cg) {
            #pragma unroll
            for (int cj = 0; cj < 4; ++cj) {
                float4 a4 = *(const float4*)&tT[cg * 276 + cj * 68 + 4 * ty];
                float4 w4 = *(const float4*)&wo[(cg * 4 + cj) * 64 + 4 * tx];
                float av[4] = {a4.x, a4.y, a4.z, a4.w};
                float wv[4] = {w4.x, w4.y, w4.z, w4.w};
                #pragma unroll
                for (int i = 0; i < 4; ++i)
                    #pragma unroll
                    for (int j = 0; j < 4; ++j)
                        acc[i][j] = fmaf(av[i], wv[j], acc[i][j]);
            }
        }

        #pragma unroll
        for (int i = 0; i < 4; ++i) {
            int gp = p0g + 4 * ty + i;
            if (gp < NPTS) {
                float4 o = make_float4(acc[i][0] + boa[0], acc[i][1] + boa[1],
                                       acc[i][2] + boa[2], acc[i][3] + boa[3]);
                ((float4*)out)[gp * 16 + tx] = o;
            }
        }
        __syncthreads();
    }
}

extern "C" void kernel_launch(void* const* d_in, const int* in_sizes, int n_in,
                              void* d_out, int out_size, void* d_ws, size_t ws_size,
                              hipStream_t stream) {
    const float* q   = (const float*)d_in[0];
    const float* k   = (const float*)d_in[1];
    const float* v   = (const float*)d_in[2];
    const float* Wq  = (const float*)d_in[3];
    const float* bq  = (const float*)d_in[4];
    const float* Wk  = (const float*)d_in[5];
    const float* bk  = (const float*)d_in[6];
    const float* Wv  = (const float*)d_in[7];
    const float* bv  = (const float*)d_in[8];
    const float* Wo  = (const float*)d_in[9];
    const float* bo  = (const float*)d_in[10];
    const int*  batch = (const int*)d_in[11];
    float* out = (float*)d_out;
    float* ws  = (float*)d_ws;

    prep_kernel<<<8, 256, 0, stream>>>(k, v, Wq, Wk, bk, Wv, bv, Wo, ws);
    passA_kernel<<<GRID, 256, 0, stream>>>(q, batch, bq, ws, out);
    passB_kernel<<<GRID, 256, 0, stream>>>(batch, bo, ws, out);
}